// Round 7
// baseline (140.436 us; speedup 1.0000x reference)
//
#include <hip/hip_runtime.h>
#include <math.h>

// Problem constants (reference: N=256, S=1, stimulus 144x256, retina 144x256)
#define NB    256
#define IMG_H 144
#define IMG_W 256
#define IMG_ELEMS (IMG_H * IMG_W)   // 36864 floats
#define FDIM  16
#define DDIM  128

#define FOV_HALF_RAD 0.6544984694978736f   // 0.5 * 75deg in rad
#define GELU_GAMMA   1.7015043497085571f
#define OUT_OF_RANGE 10.0f

typedef float f32x4 __attribute__((ext_vector_type(4)));

// jax.nn.gelu default is approximate=True (tanh form)
__device__ __forceinline__ float gelu_gamma(float x) {
    const float k0 = 0.7978845608028654f;  // sqrt(2/pi)
    const float k1 = 0.044715f;
    float t = tanhf(k0 * (x + k1 * x * x * x));
    return 0.5f * x * (1.0f + t) * GELU_GAMMA;
}

// Fused MLP -> rotation -> retina resample, NO LDS image staging.
// 512 blocks = (image, output-half); 2 blocks/CU -> 32 waves/CU (8/SIMD),
// 2x the latency hiding of the 150KiB-LDS version (which was pinned at
// 1 block/CU, all pipes <35% busy, 42.4us). Gather reads the stimulus
// directly through L1/L2 (wave footprint ~1KB, adjacent lanes share lines;
// stimulus is L3-resident across iterations - r6 FETCH was 18.8/37.7MB).
// Wave 0 computes the MLP while waves 1..15 prefetch the image into L1/L2.
__global__ void __launch_bounds__(1024, 8) fused_retina_kernel(
    const float* __restrict__ stim,   // [NB, 1, IMG_H, IMG_W]
    const float* __restrict__ persp,  // [NB, FDIM]
    const float* __restrict__ W1,     // [FDIM, DDIM]
    const float* __restrict__ b1,     // [DDIM]
    const float* __restrict__ W2,     // [DDIM, DDIM]
    const float* __restrict__ b2,     // [DDIM]
    const float* __restrict__ Wp,     // [DDIM, 3]
    const float* __restrict__ bp,     // [3]
    float* __restrict__ out)          // [NB, 1, HR, WR]
{
    __shared__ float sh1[DDIM];
    __shared__ float sR[9];

    const int tid  = threadIdx.x;
    // XCD swizzle: hw round-robins blockIdx across 8 XCDs. Map so logical
    // pairs (2n, 2n+1) = both halves of image n share an XCD, and each XCD
    // owns a contiguous 32-image chunk. 512 = 8*64 -> bijective.
    const int hw   = blockIdx.x;
    const int lg   = (hw & 7) * 64 + (hw >> 3);
    const int n    = lg >> 1;
    const int half = lg & 1;
    const int wid  = tid >> 6;
    const int lane = tid & 63;

    const float* __restrict__ img = stim + (size_t)n * IMG_ELEMS;

    if (wid > 0) {
        // ---- waves 1..15: warm L1/L2 with this image under the MLP.
        // Loads kept live via empty asm (prevents DCE, rule #17).
        const int t = tid - 64;                // 0..959
        const f32x4* __restrict__ src = (const f32x4*)img;
        float acc = 0.0f;
#pragma unroll
        for (int p = 0; p < 10; ++p) {
            const int g = t + p * 960;
            if (g < 9216) {
                f32x4 v = src[g];
                acc += v[0] + v[1] + v[2] + v[3];
            }
        }
        asm volatile("" :: "v"(acc));
    } else {
        // ---- wave 0: MLP (single-wave; lgkmcnt orders LDS within the wave)
        float a0 = b1[lane], a1 = b1[lane + 64];
#pragma unroll
        for (int f = 0; f < FDIM; ++f) {
            const float p = persp[n * FDIM + f];
            a0 = fmaf(p, W1[f * DDIM + lane],      a0);
            a1 = fmaf(p, W1[f * DDIM + lane + 64], a1);
        }
        sh1[lane]      = gelu_gamma(a0);
        sh1[lane + 64] = gelu_gamma(a1);
        asm volatile("s_waitcnt lgkmcnt(0)" ::: "memory");

        float c0 = b2[lane], c1 = b2[lane + 64];
#pragma unroll 8
        for (int k = 0; k < DDIM; ++k) {
            const float s = sh1[k];
            c0 = fmaf(s, W2[k * DDIM + lane],      c0);
            c1 = fmaf(s, W2[k * DDIM + lane + 64], c1);
        }
        const float g0 = gelu_gamma(c0);       // = h2[lane]
        const float g1 = gelu_gamma(c1);       // = h2[lane+64]

        // layer 3 wave-parallel: ang_j = sum_k h2[k]*Wp[k*3+j] + bp[j]
        float p0 = fmaf(g0, Wp[lane * 3 + 0], g1 * Wp[(lane + 64) * 3 + 0]);
        float p1 = fmaf(g0, Wp[lane * 3 + 1], g1 * Wp[(lane + 64) * 3 + 1]);
        float p2 = fmaf(g0, Wp[lane * 3 + 2], g1 * Wp[(lane + 64) * 3 + 2]);
#pragma unroll
        for (int m = 32; m >= 1; m >>= 1) {
            p0 += __shfl_xor(p0, m);
            p1 += __shfl_xor(p1, m);
            p2 += __shfl_xor(p2, m);
        }

        if (lane == 0) {
            const float ax = p0 + bp[0], ay = p1 + bp[1], az = p2 + bp[2];
            const float cx = cosf(ax), sx = sinf(ax);
            const float cy = cosf(ay), sy = sinf(ay);
            const float cz = cosf(az), sz = sinf(az);
            sR[0] = cz * cy;  sR[1] = cz * sy * sx - sz * cx;  sR[2] = cz * sy * cx + sz * sx;
            sR[3] = sz * cy;  sR[4] = sz * sy * sx + cz * cx;  sR[5] = sz * sy * cx - cz * sx;
            sR[6] = -sy;      sR[7] = cy * sx;                 sR[8] = cy * cx;
        }
    }
    __syncthreads();

    // block-uniform rotation (LDS broadcast reads, conflict-free)
    const float r0 = sR[0], r1 = sR[1], r2 = sR[2];
    const float r3 = sR[3], r4 = sR[4], r5 = sR[5];
    const float r6 = sR[6], r7 = sR[7], r8 = sR[8];

    float* __restrict__ outn = out + (size_t)n * IMG_ELEMS;

    // per-thread (column) constants; this block covers output rows
    // [half*72, half*72+72), 18 iters x 4 rows x 1024 threads
    const int w     = tid & 255;
    const int hbase = (tid >> 8) + half * 72;  // 0..3 or 72..75
    const float gx  = ((float)(2 * w + 1) - 256.0f) * (1.0f / 256.0f);
    const float axv = gx * FOV_HALF_RAD;
    const float ax2 = axv * axv;
    const float A0 = r0 * axv, A1 = r3 * axv, A2 = r6 * axv;

#pragma unroll 3
    for (int it = 0; it < 18; ++it) {
        const int h   = it * 4 + hbase;
        const int px0 = (h << 8) | w;

        const float gy  = ((float)(2 * h + 1) - 144.0f) * (1.0f / 256.0f);
        const float ayv = gy * FOV_HALF_RAD;
        const float tt  = fmaf(ayv, ayv, ax2);   // a^2 <= 0.56

        // sinc(a): even Taylor in t, |err| ~1e-8 on this range
        float sc = fmaf(tt, 2.7557319e-6f, -1.9841270e-4f);
        sc = fmaf(tt, sc,  8.3333333e-3f);
        sc = fmaf(tt, sc, -1.6666667e-1f);
        sc = fmaf(tt, sc,  1.0f);

        // cos(a): even Taylor in t
        float ca = fmaf(tt, 2.4801587e-5f, -1.3888889e-3f);
        ca = fmaf(tt, ca,  4.1666667e-2f);
        ca = fmaf(tt, ca, -0.5f);
        ca = fmaf(tt, ca,  1.0f);

        // rotated ray: r_i = sc*(R_i0*ax + R_i1*ay) + R_i2*ca
        const float rx = fmaf(sc, fmaf(r1, ayv, A0), r2 * ca);
        const float ry = fmaf(sc, fmaf(r4, ayv, A1), r5 * ca);
        const float rz = fmaf(sc, fmaf(r7, ayv, A2), r8 * ca);

        const float inv  = __builtin_amdgcn_rcpf(rz);
        const bool  safe = rz > 0.001f;
        const float gxp  = safe ? rx * inv : OUT_OF_RANGE;
        const float gyp  = safe ? ry * inv : OUT_OF_RANGE;

        const float pxf = fmaf(gxp, 128.0f, 127.5f);  // (g*256 + 255)*0.5
        const float pyf = fmaf(gyp, 128.0f, 71.5f);   // (g*256 + 143)*0.5

        const float x0f = floorf(pxf), y0f = floorf(pyf);
        const float wx  = pxf - x0f,   wy  = pyf - y0f;
        const int   x0  = (int)x0f,    y0  = (int)y0f;
        const int   x1  = x0 + 1,      y1  = y0 + 1;

        // validity per corner (reference: constant zero padding)
        const bool vx0 = (unsigned)x0 < IMG_W;
        const bool vx1 = (unsigned)x1 < IMG_W;
        const bool vy0 = (unsigned)y0 < IMG_H;
        const bool vy1 = (unsigned)y1 < IMG_H;

        // clamped addresses (always in-bounds loads; invalid values masked)
        const int xc0 = min(max(x0, 0), IMG_W - 1);
        const int xc1 = min(max(x1, 0), IMG_W - 1);
        const int yb0 = min(max(y0, 0), IMG_H - 1) << 8;   // *IMG_W
        const int yb1 = min(max(y1, 0), IMG_H - 1) << 8;

        const float l00 = img[yb0 + xc0];
        const float l01 = img[yb0 + xc1];
        const float l10 = img[yb1 + xc0];
        const float l11 = img[yb1 + xc1];

        const float c00 = (vx0 & vy0) ? l00 : 0.0f;
        const float c01 = (vx1 & vy0) ? l01 : 0.0f;
        const float c10 = (vx0 & vy1) ? l10 : 0.0f;
        const float c11 = (vx1 & vy1) ? l11 : 0.0f;

        const float top = fmaf(wx, c01 - c00, c00);
        const float bot = fmaf(wx, c11 - c10, c10);
        const float res = fmaf(wy, bot - top, top);

        __builtin_nontemporal_store(res, outn + px0);
    }
}

extern "C" void kernel_launch(void* const* d_in, const int* in_sizes, int n_in,
                              void* d_out, int out_size, void* d_ws, size_t ws_size,
                              hipStream_t stream) {
    const float* stimulus    = (const float*)d_in[0]; // [256,1,144,256]
    const float* perspective = (const float*)d_in[1]; // [256,16]
    const float* W1          = (const float*)d_in[2]; // [16,128]
    const float* b1          = (const float*)d_in[3]; // [128]
    const float* W2          = (const float*)d_in[4]; // [128,128]
    const float* b2          = (const float*)d_in[5]; // [128]
    const float* Wp          = (const float*)d_in[6]; // [128,3]
    const float* bp          = (const float*)d_in[7]; // [3]
    float* out = (float*)d_out;

    (void)d_ws; (void)ws_size;

    fused_retina_kernel<<<NB * 2, 1024, 0, stream>>>(
        stimulus, perspective, W1, b1, W2, b2, Wp, bp, out);
}